// Round 3
// baseline (492.253 us; speedup 1.0000x reference)
//
#include <hip/hip_runtime.h>

#define CROP_H 14
#define CROP_W 14
#define IMG_H 200
#define IMG_W 200
#define IMG_C 256
#define N_IMG 8
#define N_BOXES 1000
#define PLANE (IMG_H * IMG_W)       // 40000 floats
#define CPB 16                      // channels per block
#define CHUNKS (IMG_C / CPB)        // 16
#define NSLOT (2 * CROP_H)          // 28 row slots (ty,by per y)
#define BUF_STRIDE 212              // floats per row slot (53 float4, 16B-aligned stride)

// Kernel A: stable-bin the 1000 boxes by image index n (8 bins).
__global__ __launch_bounds__(512) void bin_boxes_kernel(
    const int* __restrict__ box_idx, int* __restrict__ order)
{
    __shared__ int counts[N_IMG];
    __shared__ int offsets[N_IMG];
    int tid  = threadIdx.x;
    int wave = tid >> 6;
    int lane = tid & 63;

    int cnt = 0;
    for (int i = lane; i < N_BOXES; i += 64) cnt += (box_idx[i] == wave) ? 1 : 0;
    for (int off = 32; off; off >>= 1) cnt += __shfl_down(cnt, off);
    if (lane == 0) counts[wave] = cnt;
    __syncthreads();
    if (tid == 0) {
        int s = 0;
        for (int i = 0; i < N_IMG; i++) { offsets[i] = s; s += counts[i]; }
    }
    __syncthreads();

    int base = offsets[wave];
    for (int i0 = 0; i0 < N_BOXES; i0 += 64) {
        int i = i0 + lane;
        bool p = (i < N_BOXES) && (box_idx[i] == wave);
        unsigned long long m = __ballot(p);
        unsigned long long below = m & ((1ull << lane) - 1ull);
        if (p) order[base + __popcll(below)] = i;
        base += __popcll(m);
    }
}

// Kernel B: block = (box, 16-channel chunk). Per channel: stage the box's
// 28 needed rows x contiguous col-span into LDS with coalesced float4 loads,
// then 196 threads do the bilinear taps from LDS. Boxes walk in n-grouped
// order for L2/LLC slice reuse.
__global__ __launch_bounds__(256) void crop_resize_kernel(
    const float* __restrict__ image,   // (8,256,200,200)
    const float* __restrict__ boxes,   // (1000,4)
    const int*   __restrict__ box_idx, // (1000,)
    const int*   __restrict__ order,   // (1000,) n-grouped box ids
    float*       __restrict__ out)     // (1000,256,14,14)
{
    __shared__ int   s_slotrow[NSLOT];
    __shared__ float s_yl[CROP_H];
    __shared__ int   s_ymask[CROP_H];
    __shared__ int   s_lx[CROP_W], s_rx[CROP_W];
    __shared__ float s_xl[CROP_W];
    __shared__ int   s_xmask[CROP_W];
    __shared__ int   s_xmin4, s_rowlen4, s_safe;
    __shared__ float s_rcp;
    __shared__ __align__(16) float buf[NSLOT][BUF_STRIDE];

    int tid   = threadIdx.x;
    int pos   = blockIdx.x / CHUNKS;
    int chunk = blockIdx.x % CHUNKS;
    int b     = order[pos];            // uniform per block
    int n     = box_idx[b];
    int c0    = chunk * CPB;

    float y1 = boxes[b * 4 + 0];
    float x1 = boxes[b * 4 + 1];
    float y2 = boxes[b * 4 + 2];
    float x2 = boxes[b * 4 + 3];

    // Reference arithmetic order exactly (IEEE divide, no fast-math).
    float h_scale = (y2 - y1) * (float)(IMG_H - 1) / (float)(CROP_H - 1);
    float w_scale = (x2 - x1) * (float)(IMG_W - 1) / (float)(CROP_W - 1);

    if (tid < CROP_H) {
        float in_y = y1 * (float)(IMG_H - 1) + (float)tid * h_scale;
        int m = (in_y > (float)(IMG_H - 1)) || (in_y < 0.0f);
        if (m) in_y = 0.0f;
        int ty = (int)floorf(in_y);
        int by = (int)ceilf(in_y);
        s_slotrow[2 * tid]     = ty;
        s_slotrow[2 * tid + 1] = by;
        s_yl[tid]    = in_y - (float)ty;
        s_ymask[tid] = m;
    }
    if (tid >= 16 && tid < 16 + CROP_W) {
        int x = tid - 16;
        float in_x = x1 * (float)(IMG_W - 1) + (float)x * w_scale;
        int m = (in_x > (float)(IMG_W - 1)) || (in_x < 0.0f);
        if (m) in_x = 0.0f;
        int lx = (int)floorf(in_x);
        int rx = (int)ceilf(in_x);
        s_lx[x] = lx;
        s_rx[x] = rx;
        s_xl[x] = in_x - (float)lx;
        s_xmask[x] = m;
    }
    __syncthreads();
    if (tid == 0) {
        int xmin = IMG_W, xmax = 0;
        for (int x = 0; x < CROP_W; x++) {
            xmin = min(xmin, s_lx[x]);
            xmax = max(xmax, s_rx[x]);
        }
        int xmin4 = xmin & ~3;
        int nf    = xmax - xmin4 + 1;
        int rl4   = (nf + 3) >> 2;          // <= 50
        s_xmin4   = xmin4;
        s_rowlen4 = rl4;
        s_rcp     = 1.0f / (float)rl4;
        s_safe    = (xmin4 + rl4 * 4 <= IMG_W);
    }
    __syncthreads();

    int   xmin4   = s_xmin4;
    int   rowlen4 = s_rowlen4;
    int   safe    = s_safe;
    float rcp     = s_rcp;
    int   total4  = NSLOT * rowlen4;

    size_t plane_base = ((size_t)n * IMG_C + c0) * (size_t)PLANE;
    size_t out_base   = ((size_t)b * IMG_C + c0) * (size_t)(CROP_H * CROP_W);

    for (int cc = 0; cc < CPB; ++cc) {
        const float* __restrict__ plane = image + plane_base + (size_t)cc * PLANE;

        // ---- stage: 28 rows x rowlen4 float4s, flat coalesced ----
        for (int i = tid; i < total4; i += 256) {
            int r   = (int)(((float)i + 0.5f) * rcp);   // exact floor(i/rowlen4)
            int off = i - r * rowlen4;
            int row = s_slotrow[r];
            const float* src = plane + row * IMG_W + xmin4 + off * 4;
            float4 v;
            if (safe || off != rowlen4 - 1) {
                v = *(const float4*)src;
            } else {
                int base = xmin4 + off * 4;
                const float* prow = plane + row * IMG_W;
                v.x = prow[min(base + 0, IMG_W - 1)];
                v.y = prow[min(base + 1, IMG_W - 1)];
                v.z = prow[min(base + 2, IMG_W - 1)];
                v.w = prow[min(base + 3, IMG_W - 1)];
            }
            *(float4*)&buf[r][off * 4] = v;
        }
        __syncthreads();

        // ---- compute: 196 outputs from LDS ----
        if (tid < CROP_H * CROP_W) {
            int y = tid / CROP_W;
            int x = tid % CROP_W;
            int kl = s_lx[x] - xmin4;
            int kr = s_rx[x] - xmin4;
            float xl = s_xl[x];
            float yl = s_yl[y];
            float tl = buf[2 * y][kl];
            float tr = buf[2 * y][kr];
            float bl = buf[2 * y + 1][kl];
            float br = buf[2 * y + 1][kr];
            float top = tl + xl * (tr - tl);
            float bot = bl + xl * (br - bl);
            float v = top + yl * (bot - top);
            if (s_ymask[y] | s_xmask[x]) v = 0.0f;
            out[out_base + (size_t)cc * (CROP_H * CROP_W) + tid] = v;
        }
        __syncthreads();   // protect buf before next channel's stage
    }
}

extern "C" void kernel_launch(void* const* d_in, const int* in_sizes, int n_in,
                              void* d_out, int out_size, void* d_ws, size_t ws_size,
                              hipStream_t stream) {
    const float* image   = (const float*)d_in[0];
    const float* boxes   = (const float*)d_in[1];
    const int*   box_idx = (const int*)d_in[2];
    float* out  = (float*)d_out;
    int* order  = (int*)d_ws;   // 1000 ints, rewritten every call

    bin_boxes_kernel<<<1, 512, 0, stream>>>(box_idx, order);

    int grid = N_BOXES * CHUNKS;   // 16,000 blocks
    crop_resize_kernel<<<grid, 256, 0, stream>>>(image, boxes, box_idx, order, out);
}

// Round 4
// 354.184 us; speedup vs baseline: 1.3898x; 1.3898x over previous
//
#include <hip/hip_runtime.h>

#define CROP_H 14
#define CROP_W 14
#define IMG_H 200
#define IMG_W 200
#define IMG_C 256
#define N_IMG 8
#define N_BOXES 1000
#define PLANE (IMG_H * IMG_W)            // 40000
#define HW (CROP_H * CROP_W)             // 196
#define CPT 4                            // channels per thread
#define CGRP (IMG_C / CPT)               // 64 channel groups
#define TPB_BOX (HW * CGRP)              // 12544 threads per box
#define BLK 256
#define BLOCKS_PER_BOX (TPB_BOX / BLK)   // 49

// Kernel A: stable-bin the 1000 boxes by image index n (8 bins).
__global__ __launch_bounds__(512) void bin_boxes_kernel(
    const int* __restrict__ box_idx, int* __restrict__ order)
{
    __shared__ int counts[N_IMG];
    __shared__ int offsets[N_IMG];
    int tid  = threadIdx.x;
    int wave = tid >> 6;
    int lane = tid & 63;

    int cnt = 0;
    for (int i = lane; i < N_BOXES; i += 64) cnt += (box_idx[i] == wave) ? 1 : 0;
    for (int off = 32; off; off >>= 1) cnt += __shfl_down(cnt, off);
    if (lane == 0) counts[wave] = cnt;
    __syncthreads();
    if (tid == 0) {
        int s = 0;
        for (int i = 0; i < N_IMG; i++) { offsets[i] = s; s += counts[i]; }
    }
    __syncthreads();

    int base = offsets[wave];
    for (int i0 = 0; i0 < N_BOXES; i0 += 64) {
        int i = i0 + lane;
        bool p = (i < N_BOXES) && (box_idx[i] == wave);
        unsigned long long m = __ballot(p);
        unsigned long long below = m & ((1ull << lane) - 1ull);
        if (p) order[base + __popcll(below)] = i;
        base += __popcll(m);
    }
}

// Kernel B: direct bilinear, no LDS, no barriers. Thread = (box, xy, 4
// channels): tap index math computed once, 16 independent loads in flight.
// Boxes walk in n-grouped order for L2/LLC slice reuse.
__global__ __launch_bounds__(256) void crop_resize_kernel(
    const float* __restrict__ image,   // (8,256,200,200)
    const float* __restrict__ boxes,   // (1000,4)
    const int*   __restrict__ box_idx, // (1000,)
    const int*   __restrict__ order,   // (1000,) n-grouped box ids
    float*       __restrict__ out)     // (1000,256,14,14)
{
    int pos = blockIdx.x / BLOCKS_PER_BOX;
    int sub = blockIdx.x % BLOCKS_PER_BOX;
    int b   = order[pos];                     // uniform per block
    int t   = sub * BLK + threadIdx.x;        // [0, 12544)
    int xy  = t % HW;
    int cg  = t / HW;
    int c0  = cg * CPT;
    int x   = xy % CROP_W;
    int y   = xy / CROP_W;

    float y1 = boxes[b * 4 + 0];
    float x1 = boxes[b * 4 + 1];
    float y2 = boxes[b * 4 + 2];
    float x2 = boxes[b * 4 + 3];

    // Match reference arithmetic order exactly (IEEE divide, no fast-math).
    float h_scale = (y2 - y1) * (float)(IMG_H - 1) / (float)(CROP_H - 1);
    float w_scale = (x2 - x1) * (float)(IMG_W - 1) / (float)(CROP_W - 1);

    float in_y = y1 * (float)(IMG_H - 1) + (float)y * h_scale;
    float in_x = x1 * (float)(IMG_W - 1) + (float)x * w_scale;

    float* o = out + ((size_t)b * IMG_C + c0) * (size_t)HW + xy;

    bool bad = (in_y > (float)(IMG_H - 1)) || (in_y < 0.0f) ||
               (in_x > (float)(IMG_W - 1)) || (in_x < 0.0f);
    if (bad) {
#pragma unroll
        for (int k = 0; k < CPT; k++) __builtin_nontemporal_store(0.0f, o + k * HW);
        return;
    }

    int ty = (int)floorf(in_y);
    int by = (int)ceilf(in_y);
    int lx = (int)floorf(in_x);
    int rx = (int)ceilf(in_x);
    float yl = in_y - (float)ty;
    float xl = in_x - (float)lx;

    int n = box_idx[b];
    const float* __restrict__ p0 =
        image + ((size_t)n * IMG_C + c0) * (size_t)PLANE;

    int i_tl = ty * IMG_W + lx;
    int i_tr = ty * IMG_W + rx;
    int i_bl = by * IMG_W + lx;
    int i_br = by * IMG_W + rx;

    float tl[CPT], tr[CPT], bl[CPT], br[CPT];
#pragma unroll
    for (int k = 0; k < CPT; k++) {
        const float* p = p0 + (size_t)k * PLANE;
        tl[k] = p[i_tl];
        tr[k] = p[i_tr];
        bl[k] = p[i_bl];
        br[k] = p[i_br];
    }

#pragma unroll
    for (int k = 0; k < CPT; k++) {
        float top = tl[k] + xl * (tr[k] - tl[k]);
        float bot = bl[k] + xl * (br[k] - bl[k]);
        float v   = top + yl * (bot - top);
        __builtin_nontemporal_store(v, o + k * HW);
    }
}

extern "C" void kernel_launch(void* const* d_in, const int* in_sizes, int n_in,
                              void* d_out, int out_size, void* d_ws, size_t ws_size,
                              hipStream_t stream) {
    const float* image   = (const float*)d_in[0];
    const float* boxes   = (const float*)d_in[1];
    const int*   box_idx = (const int*)d_in[2];
    float* out  = (float*)d_out;
    int* order  = (int*)d_ws;   // 1000 ints, rewritten every call

    bin_boxes_kernel<<<1, 512, 0, stream>>>(box_idx, order);

    int grid = N_BOXES * BLOCKS_PER_BOX;   // 49,000 blocks
    crop_resize_kernel<<<grid, BLK, 0, stream>>>(image, boxes, box_idx, order, out);
}

// Round 5
// 244.469 us; speedup vs baseline: 2.0136x; 1.4488x over previous
//
#include <hip/hip_runtime.h>

#define CROP_H 14
#define CROP_W 14
#define IMG_H 200
#define IMG_W 200
#define IMG_C 256
#define N_IMG 8
#define N_BOXES 1000
#define PLANE (IMG_H * IMG_W)
#define ELEMS_PER_BOX (IMG_C * CROP_H * CROP_W)   // 50176
#define BLOCKS_PER_BOX (ELEMS_PER_BOX / 256)      // 196

// Kernel A: stable-bin the 1000 boxes by image index n (8 bins).
__global__ __launch_bounds__(512) void bin_boxes_kernel(
    const int* __restrict__ box_idx, int* __restrict__ order)
{
    __shared__ int counts[N_IMG];
    __shared__ int offsets[N_IMG];
    int tid  = threadIdx.x;
    int wave = tid >> 6;
    int lane = tid & 63;

    int cnt = 0;
    for (int i = lane; i < N_BOXES; i += 64) cnt += (box_idx[i] == wave) ? 1 : 0;
    for (int off = 32; off; off >>= 1) cnt += __shfl_down(cnt, off);
    if (lane == 0) counts[wave] = cnt;
    __syncthreads();
    if (tid == 0) {
        int s = 0;
        for (int i = 0; i < N_IMG; i++) { offsets[i] = s; s += counts[i]; }
    }
    __syncthreads();

    int base = offsets[wave];
    for (int i0 = 0; i0 < N_BOXES; i0 += 64) {
        int i = i0 + lane;
        bool p = (i < N_BOXES) && (box_idx[i] == wave);
        unsigned long long m = __ballot(p);
        unsigned long long below = m & ((1ull << lane) - 1ull);
        if (p) order[base + __popcll(below)] = i;
        base += __popcll(m);
    }
}

// Kernel B: R1's direct bilinear (1 thread = 1 output element), but with the
// grid transposed to channel-chunk-major / box-minor: all resident blocks
// work on the SAME ~1.3 channels across all (n-grouped) boxes, so the live
// image working set is ~1.7 MB per XCD L2 and every fetched line is consumed
// by all overlapping boxes while still resident. Image streams ~once total.
__global__ __launch_bounds__(256) void crop_resize_kernel(
    const float* __restrict__ image,   // (8,256,200,200)
    const float* __restrict__ boxes,   // (1000,4)
    const int*   __restrict__ box_idx, // (1000,)
    const int*   __restrict__ order,   // (1000,) n-grouped box ids
    float*       __restrict__ out)     // (1000,256,14,14)
{
    int pos    = blockIdx.x % N_BOXES;          // box position (n-grouped)
    int within = blockIdx.x / N_BOXES;          // channel-chunk [0,196)
    int b      = order[pos];                    // uniform per block
    int elem   = within * 256 + threadIdx.x;    // [0, 50176)

    int x = elem % CROP_W;
    int t = elem / CROP_W;
    int y = t % CROP_H;
    int c = t / CROP_H;

    float y1 = boxes[b * 4 + 0];
    float x1 = boxes[b * 4 + 1];
    float y2 = boxes[b * 4 + 2];
    float x2 = boxes[b * 4 + 3];

    // Match reference arithmetic order exactly (IEEE divide, no fast-math).
    float h_scale = (y2 - y1) * (float)(IMG_H - 1) / (float)(CROP_H - 1);
    float w_scale = (x2 - x1) * (float)(IMG_W - 1) / (float)(CROP_W - 1);

    float in_y = y1 * (float)(IMG_H - 1) + (float)y * h_scale;
    float in_x = x1 * (float)(IMG_W - 1) + (float)x * w_scale;

    size_t oidx = (size_t)b * ELEMS_PER_BOX + elem;

    bool bad = (in_y > (float)(IMG_H - 1)) || (in_y < 0.0f) ||
               (in_x > (float)(IMG_W - 1)) || (in_x < 0.0f);
    if (bad) { __builtin_nontemporal_store(0.0f, &out[oidx]); return; }

    int ty = (int)floorf(in_y);
    int by = (int)ceilf(in_y);
    int lx = (int)floorf(in_x);
    int rx = (int)ceilf(in_x);
    float yl = in_y - (float)ty;
    float xl = in_x - (float)lx;

    int n = box_idx[b];
    const float* __restrict__ plane =
        image + ((size_t)n * IMG_C + c) * (size_t)PLANE;

    float tl = plane[ty * IMG_W + lx];
    float tr = plane[ty * IMG_W + rx];
    float bl = plane[by * IMG_W + lx];
    float br = plane[by * IMG_W + rx];

    float top = tl + xl * (tr - tl);
    float bot = bl + xl * (br - bl);
    float v   = top + yl * (bot - top);
    __builtin_nontemporal_store(v, &out[oidx]);
}

extern "C" void kernel_launch(void* const* d_in, const int* in_sizes, int n_in,
                              void* d_out, int out_size, void* d_ws, size_t ws_size,
                              hipStream_t stream) {
    const float* image   = (const float*)d_in[0];
    const float* boxes   = (const float*)d_in[1];
    const int*   box_idx = (const int*)d_in[2];
    float* out  = (float*)d_out;
    int* order  = (int*)d_ws;   // 1000 ints, rewritten every call

    bin_boxes_kernel<<<1, 512, 0, stream>>>(box_idx, order);

    int grid = N_BOXES * BLOCKS_PER_BOX;  // 196,000 blocks
    crop_resize_kernel<<<grid, 256, 0, stream>>>(image, boxes, box_idx, order, out);
}